// Round 2
// baseline (728.790 us; speedup 1.0000x reference)
//
#include <hip/hip_runtime.h>

#define N_TOK 4096
#define HEAD_D 64
#define CCH 128
#define QK_SCALE 0.08838834764831845f  // 128^-0.5 (reference scales by C, not head_c)

__device__ __forceinline__ float4 ld4(const float* p) {
    return *reinterpret_cast<const float4*>(p);
}

// ---------------- Kernel 1: QKV projection ----------------
// x:[16384,128] @ wqkv:[128,384] -> scatter into Q/K/V [(b*2+h)*4096+n][64]
// grid (256, 6): blockIdx.x = 64-row tile, blockIdx.y = 64-col tile.
__global__ __launch_bounds__(256) void k_qkv(const float* __restrict__ x,
                                             const float* __restrict__ wqkv,
                                             float* __restrict__ Q,
                                             float* __restrict__ K,
                                             float* __restrict__ V) {
    __shared__ float xs[64][132];   // rows 16B-aligned; b128 broadcast reads
    __shared__ float ws[128][68];   // b128 reads along cols, even bank spread
    const int t  = threadIdx.x;
    const int mt = blockIdx.x;
    const int nt = blockIdx.y;

    #pragma unroll
    for (int f = 0; f < 8; ++f) {                 // 64x128 x-tile
        int g = f * 256 + t;
        int r = g >> 5, c = (g & 31) << 2;
        *reinterpret_cast<float4*>(&xs[r][c]) = ld4(&x[(mt * 64 + r) * CCH + c]);
    }
    #pragma unroll
    for (int f = 0; f < 8; ++f) {                 // 128x64 w-tile
        int g = f * 256 + t;
        int r = g >> 4, c = (g & 15) << 2;
        *reinterpret_cast<float4*>(&ws[r][c]) = ld4(&wqkv[r * 384 + nt * 64 + c]);
    }
    __syncthreads();

    const int r0 = (t >> 4) << 2;
    const int c0 = (t & 15) << 2;
    float acc[4][4] = {};
    #pragma unroll 8
    for (int k4 = 0; k4 < 32; ++k4) {
        float a[4][4], b[4][4];
        #pragma unroll
        for (int i = 0; i < 4; ++i) {
            float4 v = ld4(&xs[r0 + i][k4 * 4]);
            a[i][0] = v.x; a[i][1] = v.y; a[i][2] = v.z; a[i][3] = v.w;
        }
        #pragma unroll
        for (int kk = 0; kk < 4; ++kk) {
            float4 v = ld4(&ws[k4 * 4 + kk][c0]);
            b[kk][0] = v.x; b[kk][1] = v.y; b[kk][2] = v.z; b[kk][3] = v.w;
        }
        #pragma unroll
        for (int i = 0; i < 4; ++i)
            #pragma unroll
            for (int kk = 0; kk < 4; ++kk)
                #pragma unroll
                for (int j = 0; j < 4; ++j)
                    acc[i][j] += a[i][kk] * b[kk][j];
    }

    const int head = nt / 3;
    const int which = nt - 3 * head;
    float* dst = (which == 0) ? Q : (which == 1 ? K : V);
    #pragma unroll
    for (int i = 0; i < 4; ++i) {
        int gi = mt * 64 + r0 + i;      // global token row in [0,16384)
        int bb = gi >> 12;              // batch
        int n  = gi & 4095;             // token within batch
        float4 v = make_float4(acc[i][0], acc[i][1], acc[i][2], acc[i][3]);
        *reinterpret_cast<float4*>(&dst[((bb * 2 + head) * N_TOK + n) * HEAD_D + c0]) = v;
    }
}

// ---------------- Kernel 2: flash attention ----------------
// grid (64, 8): blockIdx.x = q-tile (64 rows), blockIdx.y = (b*2+h).
// 256 threads; thread owns 4x4 of the 64x64 S tile.
// Ks is XOR-swizzled (slot ^= (row>>2)&7) so the b128 K-fragment reads are
// even-spread across bank groups (verified 2 words/bank on read & write).
__global__ __launch_bounds__(256) void k_attn(const float* __restrict__ Q,
                                              const float* __restrict__ K,
                                              const float* __restrict__ V,
                                              float* __restrict__ R) {
    __shared__ float Qs[64][68];   // [row][d]     b128 broadcast reads
    __shared__ float Ks[64][68];   // [col][swz d] b128 reads, swizzled
    __shared__ float Vs[64][68];   // [j][d]       b128 reads
    __shared__ float Ps[64][68];   // [j][row]     P^T

    const int t  = threadIdx.x;
    const int qt = blockIdx.x;
    const int bh = blockIdx.y;
    const float* Qp = Q + (size_t)bh * N_TOK * HEAD_D + qt * 64 * HEAD_D;
    const float* Kp = K + (size_t)bh * N_TOK * HEAD_D;
    const float* Vp = V + (size_t)bh * N_TOK * HEAD_D;

    // Q tile (scale folded in)
    #pragma unroll
    for (int f = 0; f < 4; ++f) {
        int g = f * 256 + t;
        int r = g >> 4, c = (g & 15) << 2;
        float4 v = ld4(&Qp[r * HEAD_D + c]);
        Qs[r][c]     = v.x * QK_SCALE;
        Qs[r][c + 1] = v.y * QK_SCALE;
        Qs[r][c + 2] = v.z * QK_SCALE;
        Qs[r][c + 3] = v.w * QK_SCALE;
    }

    const int r0 = (t >> 4) << 2;
    const int c0 = (t & 15) << 2;
    const int swz = t & 7;          // == ((c0+j)>>2)&7 for j in 0..3
    float m[4], l[4], o[4][4];
    #pragma unroll
    for (int i = 0; i < 4; ++i) {
        m[i] = -1e30f; l[i] = 0.f;
        #pragma unroll
        for (int j = 0; j < 4; ++j) o[i][j] = 0.f;
    }

    for (int kt = 0; kt < 64; ++kt) {
        __syncthreads();  // previous iter done reading Ks/Vs/Ps (covers Qs on kt=0)
        #pragma unroll
        for (int f = 0; f < 4; ++f) {
            int g = f * 256 + t;
            int r = g >> 4, s = g & 15;
            float4 kv = ld4(&Kp[(kt * 64 + r) * HEAD_D + s * 4]);
            *reinterpret_cast<float4*>(&Ks[r][(s ^ ((r >> 2) & 7)) * 4]) = kv;
            float4 vv = ld4(&Vp[(kt * 64 + r) * HEAD_D + s * 4]);
            *reinterpret_cast<float4*>(&Vs[r][s * 4]) = vv;
        }
        __syncthreads();

        // S = (Q*scale) K^T   (64x64, 4x4 per thread), b128 operand reads
        float s[4][4] = {};
        #pragma unroll 4
        for (int d4 = 0; d4 < 16; ++d4) {
            float a[4][4], b[4][4];
            #pragma unroll
            for (int i = 0; i < 4; ++i) {
                float4 v = ld4(&Qs[r0 + i][d4 * 4]);
                a[i][0] = v.x; a[i][1] = v.y; a[i][2] = v.z; a[i][3] = v.w;
            }
            #pragma unroll
            for (int j = 0; j < 4; ++j) {
                float4 v = ld4(&Ks[c0 + j][((d4 ^ swz) * 4)]);
                b[j][0] = v.x; b[j][1] = v.y; b[j][2] = v.z; b[j][3] = v.w;
            }
            #pragma unroll
            for (int i = 0; i < 4; ++i)
                #pragma unroll
                for (int j = 0; j < 4; ++j)
                    s[i][j] += a[i][0] * b[j][0] + a[i][1] * b[j][1]
                             + a[i][2] * b[j][2] + a[i][3] * b[j][3];
        }

        // online softmax (row groups = 16 consecutive lanes)
        #pragma unroll
        for (int i = 0; i < 4; ++i) {
            float mx = fmaxf(fmaxf(s[i][0], s[i][1]), fmaxf(s[i][2], s[i][3]));
            mx = fmaxf(mx, __shfl_xor(mx, 1));
            mx = fmaxf(mx, __shfl_xor(mx, 2));
            mx = fmaxf(mx, __shfl_xor(mx, 4));
            mx = fmaxf(mx, __shfl_xor(mx, 8));
            float mn = fmaxf(m[i], mx);
            float corr = __expf(m[i] - mn);
            float sum = 0.f;
            #pragma unroll
            for (int j = 0; j < 4; ++j) {
                s[i][j] = __expf(s[i][j] - mn);
                sum += s[i][j];
            }
            sum += __shfl_xor(sum, 1);
            sum += __shfl_xor(sum, 2);
            sum += __shfl_xor(sum, 4);
            sum += __shfl_xor(sum, 8);
            l[i] = l[i] * corr + sum;
            m[i] = mn;
            #pragma unroll
            for (int j = 0; j < 4; ++j) o[i][j] *= corr;
        }

        // write P^T to LDS
        #pragma unroll
        for (int j = 0; j < 4; ++j) {
            float4 v = make_float4(s[0][j], s[1][j], s[2][j], s[3][j]);
            *reinterpret_cast<float4*>(&Ps[c0 + j][r0]) = v;
        }
        __syncthreads();

        // O += P V   (thread: rows r0.., dims c0..)
        #pragma unroll 2
        for (int j = 0; j < 64; ++j) {
            float4 p = ld4(&Ps[j][r0]);
            float4 v = ld4(&Vs[j][c0]);
            o[0][0] += p.x * v.x; o[0][1] += p.x * v.y; o[0][2] += p.x * v.z; o[0][3] += p.x * v.w;
            o[1][0] += p.y * v.x; o[1][1] += p.y * v.y; o[1][2] += p.y * v.z; o[1][3] += p.y * v.w;
            o[2][0] += p.z * v.x; o[2][1] += p.z * v.y; o[2][2] += p.z * v.z; o[2][3] += p.z * v.w;
            o[3][0] += p.w * v.x; o[3][1] += p.w * v.y; o[3][2] += p.w * v.z; o[3][3] += p.w * v.w;
        }
    }

    // epilogue: R[b*4096+n][h*64 + d]
    const int b = bh >> 1, h = bh & 1;
    #pragma unroll
    for (int i = 0; i < 4; ++i) {
        float inv = 1.0f / l[i];
        int gi = b * N_TOK + qt * 64 + r0 + i;
        float4 v = make_float4(o[i][0] * inv, o[i][1] * inv, o[i][2] * inv, o[i][3] * inv);
        *reinterpret_cast<float4*>(&R[(size_t)gi * CCH + h * HEAD_D + c0]) = v;
    }
}

// ---------------- Kernel 3: output projection + bias ----------------
// R:[16384,128] @ wout:[128,128] + bout -> out
__global__ __launch_bounds__(256) void k_out(const float* __restrict__ R,
                                             const float* __restrict__ wout,
                                             const float* __restrict__ bout,
                                             float* __restrict__ out) {
    __shared__ float xs[64][132];
    __shared__ float ws[128][68];
    const int t  = threadIdx.x;
    const int mt = blockIdx.x;
    const int nt = blockIdx.y;

    #pragma unroll
    for (int f = 0; f < 8; ++f) {
        int g = f * 256 + t;
        int r = g >> 5, c = (g & 31) << 2;
        *reinterpret_cast<float4*>(&xs[r][c]) = ld4(&R[(mt * 64 + r) * CCH + c]);
    }
    #pragma unroll
    for (int f = 0; f < 8; ++f) {
        int g = f * 256 + t;
        int r = g >> 4, c = (g & 15) << 2;
        *reinterpret_cast<float4*>(&ws[r][c]) = ld4(&wout[r * CCH + nt * 64 + c]);
    }
    __syncthreads();

    const int r0 = (t >> 4) << 2;
    const int c0 = (t & 15) << 2;
    float acc[4][4] = {};
    #pragma unroll 8
    for (int k4 = 0; k4 < 32; ++k4) {
        float a[4][4], b[4][4];
        #pragma unroll
        for (int i = 0; i < 4; ++i) {
            float4 v = ld4(&xs[r0 + i][k4 * 4]);
            a[i][0] = v.x; a[i][1] = v.y; a[i][2] = v.z; a[i][3] = v.w;
        }
        #pragma unroll
        for (int kk = 0; kk < 4; ++kk) {
            float4 v = ld4(&ws[k4 * 4 + kk][c0]);
            b[kk][0] = v.x; b[kk][1] = v.y; b[kk][2] = v.z; b[kk][3] = v.w;
        }
        #pragma unroll
        for (int i = 0; i < 4; ++i)
            #pragma unroll
            for (int kk = 0; kk < 4; ++kk)
                #pragma unroll
                for (int j = 0; j < 4; ++j)
                    acc[i][j] += a[i][kk] * b[kk][j];
    }

    float4 bias = ld4(&bout[nt * 64 + c0]);
    #pragma unroll
    for (int i = 0; i < 4; ++i) {
        int gi = mt * 64 + r0 + i;
        float4 v = make_float4(acc[i][0] + bias.x, acc[i][1] + bias.y,
                               acc[i][2] + bias.z, acc[i][3] + bias.w);
        *reinterpret_cast<float4*>(&out[(size_t)gi * CCH + nt * 64 + c0]) = v;
    }
}

extern "C" void kernel_launch(void* const* d_in, const int* in_sizes, int n_in,
                              void* d_out, int out_size, void* d_ws, size_t ws_size,
                              hipStream_t stream) {
    const float* x    = (const float*)d_in[0];
    const float* wqkv = (const float*)d_in[1];
    const float* wout = (const float*)d_in[2];
    const float* bout = (const float*)d_in[3];
    float* out = (float*)d_out;
    float* wsf = (float*)d_ws;

    // workspace layout (floats): Q,K,V each 4*2*4096*64 = 2,097,152; R = 16384*128
    float* Q = wsf;
    float* K = wsf + 2097152;
    float* V = wsf + 4194304;
    float* R = wsf + 6291456;   // total 32 MB

    k_qkv<<<dim3(256, 6), 256, 0, stream>>>(x, wqkv, Q, K, V);
    k_attn<<<dim3(64, 8), 256, 0, stream>>>(Q, K, V, R);
    k_out<<<dim3(256, 2), 256, 0, stream>>>(R, wout, bout, out);
}

// Round 6
// 239.392 us; speedup vs baseline: 3.0443x; 3.0443x over previous
//
#include <hip/hip_runtime.h>

#define NT 4096
#define HD 64
#define CCH 128
#define QK_SCALE 0.08838834764831845f  // 128^-0.5 (reference scales by C, not head_c)

typedef __attribute__((ext_vector_type(8))) short short8;   // 8 bf16 (4 VGPR)
typedef __attribute__((ext_vector_type(4))) short short4v;  // 4 bf16
typedef __attribute__((ext_vector_type(4))) float f32x4;

__device__ __forceinline__ float4 ld4(const float* p) {
    return *reinterpret_cast<const float4*>(p);
}

__device__ __forceinline__ unsigned short f2bf(float f) {  // RNE float->bf16
    union { float f; unsigned u; } v; v.f = f;
    unsigned r = v.u + 0x7fff + ((v.u >> 16) & 1);
    return (unsigned short)(r >> 16);
}

// ---------------- Kernel 1: QKV projection (fp32 math, bf16 outputs) ----------
// x:[16384,128] @ wqkv:[128,384] -> Qb (scaled bf16 [bh][n][d]), Kb (bf16 [bh][n][d]),
// Vt (bf16 TRANSPOSED [bh][d][n]).
__global__ __launch_bounds__(256) void k_qkv(const float* __restrict__ x,
                                             const float* __restrict__ wqkv,
                                             unsigned short* __restrict__ Qb,
                                             unsigned short* __restrict__ Kb,
                                             unsigned short* __restrict__ Vt) {
    __shared__ float xs[64][132];
    __shared__ float ws[128][68];
    const int t  = threadIdx.x;
    const int mt = blockIdx.x;
    const int nt = blockIdx.y;

    #pragma unroll
    for (int f = 0; f < 8; ++f) {
        int g = f * 256 + t;
        int r = g >> 5, c = (g & 31) << 2;
        *reinterpret_cast<float4*>(&xs[r][c]) = ld4(&x[(mt * 64 + r) * CCH + c]);
    }
    #pragma unroll
    for (int f = 0; f < 8; ++f) {
        int g = f * 256 + t;
        int r = g >> 4, c = (g & 15) << 2;
        *reinterpret_cast<float4*>(&ws[r][c]) = ld4(&wqkv[r * 384 + nt * 64 + c]);
    }
    __syncthreads();

    const int r0 = (t >> 4) << 2;
    const int c0 = (t & 15) << 2;
    float acc[4][4] = {};
    #pragma unroll 8
    for (int k4 = 0; k4 < 32; ++k4) {
        float a[4][4], b[4][4];
        #pragma unroll
        for (int i = 0; i < 4; ++i) {
            float4 v = ld4(&xs[r0 + i][k4 * 4]);
            a[i][0] = v.x; a[i][1] = v.y; a[i][2] = v.z; a[i][3] = v.w;
        }
        #pragma unroll
        for (int kk = 0; kk < 4; ++kk) {
            float4 v = ld4(&ws[k4 * 4 + kk][c0]);
            b[kk][0] = v.x; b[kk][1] = v.y; b[kk][2] = v.z; b[kk][3] = v.w;
        }
        #pragma unroll
        for (int i = 0; i < 4; ++i)
            #pragma unroll
            for (int kk = 0; kk < 4; ++kk)
                #pragma unroll
                for (int j = 0; j < 4; ++j)
                    acc[i][j] += a[i][kk] * b[kk][j];
    }

    const int head  = nt / 3;
    const int which = nt - 3 * head;
    const int gi0 = mt * 64 + r0;
    const int bb  = gi0 >> 12;
    const int n0  = gi0 & 4095;
    const int bhh = bb * 2 + head;

    if (which == 0) {              // Q, scale folded
        #pragma unroll
        for (int i = 0; i < 4; ++i) {
            uint2 u;
            u.x = f2bf(acc[i][0] * QK_SCALE) | ((unsigned)f2bf(acc[i][1] * QK_SCALE) << 16);
            u.y = f2bf(acc[i][2] * QK_SCALE) | ((unsigned)f2bf(acc[i][3] * QK_SCALE) << 16);
            *reinterpret_cast<uint2*>(&Qb[((size_t)(bhh * NT + n0 + i)) * HD + c0]) = u;
        }
    } else if (which == 1) {       // K
        #pragma unroll
        for (int i = 0; i < 4; ++i) {
            uint2 u;
            u.x = f2bf(acc[i][0]) | ((unsigned)f2bf(acc[i][1]) << 16);
            u.y = f2bf(acc[i][2]) | ((unsigned)f2bf(acc[i][3]) << 16);
            *reinterpret_cast<uint2*>(&Kb[((size_t)(bhh * NT + n0 + i)) * HD + c0]) = u;
        }
    } else {                       // V, transposed store [d][n]
        #pragma unroll
        for (int jj = 0; jj < 4; ++jj) {
            uint2 u;
            u.x = f2bf(acc[0][jj]) | ((unsigned)f2bf(acc[1][jj]) << 16);
            u.y = f2bf(acc[2][jj]) | ((unsigned)f2bf(acc[3][jj]) << 16);
            *reinterpret_cast<uint2*>(&Vt[((size_t)(bhh * HD + c0 + jj)) * NT + n0]) = u;
        }
    }
}

// ---------------- Kernel 2: flash attention, bf16 MFMA ----------------
// grid (64, 8): blockIdx.x = 64-row q-tile, blockIdx.y = bh. 4 waves x 16 q-rows.
// K tile [64][64] & Vt tile [64][64] bf16 in LDS, XOR-swizzled via pre-swizzled
// global source + linear global_load_lds (both-sides involution, guide rule 21).
// P strip per wave: [16][68] bf16 (136B stride: b16 writes & b64 reads conflict-free).
__global__ __launch_bounds__(256) void k_attn(const unsigned short* __restrict__ Qb,
                                              const unsigned short* __restrict__ Kb,
                                              const unsigned short* __restrict__ Vt,
                                              float* __restrict__ R) {
    __shared__ __align__(16) char smem[41472];
    char* KsB = smem;             // [2][8192]
    char* VsB = smem + 16384;     // [2][8192]
    char* PwA = smem + 32768;     // [4][2176]

    const int t    = threadIdx.x;
    const int lane = t & 63;
    const int w    = t >> 6;
    const int qt   = blockIdx.x;
    const int bh   = blockIdx.y;

    const char* KbT = (const char*)Kb + (size_t)bh * NT * HD * 2;
    const char* VtT = (const char*)Vt + (size_t)bh * HD * NT * 2;

    // Q A-fragments held in registers: lane -> Q[row = l&15][k = (l>>4)*8 + j + 32*ks]
    short8 qa[2];
    {
        const int qrow = qt * 64 + w * 16 + (lane & 15);
        const char* qp = (const char*)Qb +
            (((size_t)bh * NT + qrow) * HD + ((lane >> 4) * 8)) * 2;
        qa[0] = *reinterpret_cast<const short8*>(qp);
        qa[1] = *reinterpret_cast<const short8*>(qp + 64);
    }

    char* Pw = PwA + w * 2176;

    float mrow[4], lrow[4];
    f32x4 oacc[4];
    #pragma unroll
    for (int i = 0; i < 4; ++i) {
        mrow[i] = -1e30f; lrow[i] = 0.f;
        oacc[i] = (f32x4)0.f;
    }

    const int rc0 = t >> 3;        // staging row for issue 0 (0..31)
    const int sp  = t & 7;         // physical slot
    const int rc1 = rc0 + 32;      // staging row for issue 1

    auto stage = [&](int buf, int kt) {
        const char* ksrc = KbT + (size_t)kt * 64 * 128;   // K rows kt*64.., 128B/row
        const char* vsrc = VtT + (size_t)kt * 128;        // Vt: d*8192 + kt*128
        __builtin_amdgcn_global_load_lds(
            (const __attribute__((address_space(1))) void*)(ksrc + rc0 * 128 + ((sp ^ (rc0 & 7)) * 16)),
            (__attribute__((address_space(3))) void*)(KsB + buf * 8192 + t * 16), 16, 0, 0);
        __builtin_amdgcn_global_load_lds(
            (const __attribute__((address_space(1))) void*)(ksrc + rc1 * 128 + ((sp ^ (rc1 & 7)) * 16)),
            (__attribute__((address_space(3))) void*)(KsB + buf * 8192 + 4096 + t * 16), 16, 0, 0);
        __builtin_amdgcn_global_load_lds(
            (const __attribute__((address_space(1))) void*)(vsrc + (size_t)rc0 * 8192 + ((sp ^ (rc0 & 7)) * 16)),
            (__attribute__((address_space(3))) void*)(VsB + buf * 8192 + t * 16), 16, 0, 0);
        __builtin_amdgcn_global_load_lds(
            (const __attribute__((address_space(1))) void*)(vsrc + (size_t)rc1 * 8192 + ((sp ^ (rc1 & 7)) * 16)),
            (__attribute__((address_space(3))) void*)(VsB + buf * 8192 + 4096 + t * 16), 16, 0, 0);
    };

    int cur = 0;
    stage(0, 0);
    __syncthreads();   // drains vmcnt -> tile 0 resident

    for (int kt = 0; kt < 64; ++kt) {
        if (kt < 63) stage(cur ^ 1, kt + 1);

        const char* KsC = KsB + cur * 8192;
        const char* VsC = VsB + cur * 8192;

        // ---- S = (Q*scale) K^T : 4 col-tiles x 2 k-steps of 16x16x32 ----
        f32x4 sacc[4];
        #pragma unroll
        for (int ct = 0; ct < 4; ++ct) sacc[ct] = (f32x4)0.f;
        #pragma unroll
        for (int ct = 0; ct < 4; ++ct) {
            const int j = ct * 16 + (lane & 15);
            #pragma unroll
            for (int ks = 0; ks < 2; ++ks) {
                const int slot = ((lane >> 4) + 4 * ks) ^ (lane & 7);
                short8 kb = *reinterpret_cast<const short8*>(KsC + j * 128 + slot * 16);
                sacc[ct] = __builtin_amdgcn_mfma_f32_16x16x32_bf16(qa[ks], kb, sacc[ct], 0, 0, 0);
            }
        }

        // ---- online softmax on C/D frags (row = (l>>4)*4+r, col = ct*16 + (l&15)) ----
        #pragma unroll
        for (int r = 0; r < 4; ++r) {
            float mx = fmaxf(fmaxf(sacc[0][r], sacc[1][r]), fmaxf(sacc[2][r], sacc[3][r]));
            mx = fmaxf(mx, __shfl_xor(mx, 1));
            mx = fmaxf(mx, __shfl_xor(mx, 2));
            mx = fmaxf(mx, __shfl_xor(mx, 4));
            mx = fmaxf(mx, __shfl_xor(mx, 8));
            const float mn = fmaxf(mrow[r], mx);
            const float corr = __expf(mrow[r] - mn);
            mrow[r] = mn;
            float p0 = __expf(sacc[0][r] - mn);
            float p1 = __expf(sacc[1][r] - mn);
            float p2 = __expf(sacc[2][r] - mn);
            float p3 = __expf(sacc[3][r] - mn);
            float sum = p0 + p1 + p2 + p3;
            sum += __shfl_xor(sum, 1);
            sum += __shfl_xor(sum, 2);
            sum += __shfl_xor(sum, 4);
            sum += __shfl_xor(sum, 8);
            lrow[r] = lrow[r] * corr + sum;
            #pragma unroll
            for (int dt = 0; dt < 4; ++dt) oacc[dt][r] *= corr;
            // write P (bf16) to wave-private strip
            const int rowoff = ((lane >> 4) * 4 + r) * 136;
            const int cb = (lane & 15) * 2;
            *reinterpret_cast<unsigned short*>(Pw + rowoff + cb)      = f2bf(p0);
            *reinterpret_cast<unsigned short*>(Pw + rowoff + 32 + cb) = f2bf(p1);
            *reinterpret_cast<unsigned short*>(Pw + rowoff + 64 + cb) = f2bf(p2);
            *reinterpret_cast<unsigned short*>(Pw + rowoff + 96 + cb) = f2bf(p3);
        }

        // ---- P A-frags (wave-local LDS round-trip; compiler inserts lgkmcnt) ----
        short8 pa[2];
        #pragma unroll
        for (int ks = 0; ks < 2; ++ks) {
            const char* pp = Pw + (lane & 15) * 136 + (lane >> 4) * 16 + 64 * ks;
            short4v lo = *reinterpret_cast<const short4v*>(pp);
            short4v hi = *reinterpret_cast<const short4v*>(pp + 8);
            short8 a;
            a[0] = lo[0]; a[1] = lo[1]; a[2] = lo[2]; a[3] = lo[3];
            a[4] = hi[0]; a[5] = hi[1]; a[6] = hi[2]; a[7] = hi[3];
            pa[ks] = a;
        }

        // ---- O += P V : 4 d-tiles x 2 k-steps ----
        #pragma unroll
        for (int dt = 0; dt < 4; ++dt) {
            const int d = dt * 16 + (lane & 15);
            #pragma unroll
            for (int ks = 0; ks < 2; ++ks) {
                const int slot = ((lane >> 4) + 4 * ks) ^ (lane & 7);
                short8 vb = *reinterpret_cast<const short8*>(VsC + d * 128 + slot * 16);
                oacc[dt] = __builtin_amdgcn_mfma_f32_16x16x32_bf16(pa[ks], vb, oacc[dt], 0, 0, 0);
            }
        }

        __syncthreads();   // drain next-tile staging; protect cur before reuse
        cur ^= 1;
    }

    // ---- epilogue: R[b*4096+n][h*64 + d] (fp32) ----
    const int b = bh >> 1, h = bh & 1;
    #pragma unroll
    for (int r = 0; r < 4; ++r) {
        const float inv = 1.0f / lrow[r];
        const int row = qt * 64 + w * 16 + (lane >> 4) * 4 + r;
        float* dst = &R[((size_t)(b * NT + row)) * CCH + h * HD];
        #pragma unroll
        for (int dt = 0; dt < 4; ++dt)
            dst[dt * 16 + (lane & 15)] = oacc[dt][r] * inv;
    }
}

// ---------------- Kernel 3: output projection + bias (fp32) ----------------
__global__ __launch_bounds__(256) void k_out(const float* __restrict__ R,
                                             const float* __restrict__ wout,
                                             const float* __restrict__ bout,
                                             float* __restrict__ out) {
    __shared__ float xs[64][132];
    __shared__ float ws[128][68];
    const int t  = threadIdx.x;
    const int mt = blockIdx.x;
    const int nt = blockIdx.y;

    #pragma unroll
    for (int f = 0; f < 8; ++f) {
        int g = f * 256 + t;
        int r = g >> 5, c = (g & 31) << 2;
        *reinterpret_cast<float4*>(&xs[r][c]) = ld4(&R[(mt * 64 + r) * CCH + c]);
    }
    #pragma unroll
    for (int f = 0; f < 8; ++f) {
        int g = f * 256 + t;
        int r = g >> 4, c = (g & 15) << 2;
        *reinterpret_cast<float4*>(&ws[r][c]) = ld4(&wout[r * CCH + nt * 64 + c]);
    }
    __syncthreads();

    const int r0 = (t >> 4) << 2;
    const int c0 = (t & 15) << 2;
    float acc[4][4] = {};
    #pragma unroll 8
    for (int k4 = 0; k4 < 32; ++k4) {
        float a[4][4], b[4][4];
        #pragma unroll
        for (int i = 0; i < 4; ++i) {
            float4 v = ld4(&xs[r0 + i][k4 * 4]);
            a[i][0] = v.x; a[i][1] = v.y; a[i][2] = v.z; a[i][3] = v.w;
        }
        #pragma unroll
        for (int kk = 0; kk < 4; ++kk) {
            float4 v = ld4(&ws[k4 * 4 + kk][c0]);
            b[kk][0] = v.x; b[kk][1] = v.y; b[kk][2] = v.z; b[kk][3] = v.w;
        }
        #pragma unroll
        for (int i = 0; i < 4; ++i)
            #pragma unroll
            for (int kk = 0; kk < 4; ++kk)
                #pragma unroll
                for (int j = 0; j < 4; ++j)
                    acc[i][j] += a[i][kk] * b[kk][j];
    }

    float4 bias = ld4(&bout[nt * 64 + c0]);
    #pragma unroll
    for (int i = 0; i < 4; ++i) {
        int gi = mt * 64 + r0 + i;
        float4 v = make_float4(acc[i][0] + bias.x, acc[i][1] + bias.y,
                               acc[i][2] + bias.z, acc[i][3] + bias.w);
        *reinterpret_cast<float4*>(&out[(size_t)gi * CCH + nt * 64 + c0]) = v;
    }
}

extern "C" void kernel_launch(void* const* d_in, const int* in_sizes, int n_in,
                              void* d_out, int out_size, void* d_ws, size_t ws_size,
                              hipStream_t stream) {
    const float* x    = (const float*)d_in[0];
    const float* wqkv = (const float*)d_in[1];
    const float* wout = (const float*)d_in[2];
    const float* bout = (const float*)d_in[3];
    float* out = (float*)d_out;

    // workspace: Qb/Kb/Vt bf16 (4MB each), R fp32 (8MB) = 20MB
    unsigned short* Qb = (unsigned short*)d_ws;
    unsigned short* Kb = Qb + 2097152;
    unsigned short* Vt = Kb + 2097152;
    float* R = (float*)((char*)d_ws + 12 * 1024 * 1024);

    k_qkv<<<dim3(256, 6), 256, 0, stream>>>(x, wqkv, Qb, Kb, Vt);
    k_attn<<<dim3(64, 8), 256, 0, stream>>>(Qb, Kb, Vt, R);
    k_out<<<dim3(256, 2), 256, 0, stream>>>(R, wout, bout, out);
}

// Round 9
// 193.530 us; speedup vs baseline: 3.7658x; 1.2370x over previous
//
#include <hip/hip_runtime.h>
#include <hip/hip_bf16.h>

#define NT 4096
#define HD 64
#define CCH 128
#define QK_SCALE 0.08838834764831845f  // 128^-0.5 (reference scales by C, not head_c)

typedef __attribute__((ext_vector_type(8))) short short8;   // 8 bf16 (4 VGPR)
typedef __attribute__((ext_vector_type(4))) float f32x4;

__device__ __forceinline__ float4 ld4(const float* p) {
    return *reinterpret_cast<const float4*>(p);
}

__device__ __forceinline__ unsigned short f2bf(float f) {  // RNE float->bf16
    union { float f; unsigned u; } v; v.f = f;
    unsigned r = v.u + 0x7fff + ((v.u >> 16) & 1);
    return (unsigned short)(r >> 16);
}

// ---------------- Kernel 1: QKV projection (fp32 math, bf16 outputs) ----------
// x:[16384,128] @ wqkv:[128,384] -> Qb (scaled bf16 [bh][n][d]), Kb (bf16 [bh][n][d]),
// Vt (bf16 TRANSPOSED [bh][d][n]).
__global__ __launch_bounds__(256) void k_qkv(const float* __restrict__ x,
                                             const float* __restrict__ wqkv,
                                             unsigned short* __restrict__ Qb,
                                             unsigned short* __restrict__ Kb,
                                             unsigned short* __restrict__ Vt) {
    __shared__ float xs[64][132];
    __shared__ float ws[128][68];
    const int t  = threadIdx.x;
    const int mt = blockIdx.x;
    const int nt = blockIdx.y;

    #pragma unroll
    for (int f = 0; f < 8; ++f) {
        int g = f * 256 + t;
        int r = g >> 5, c = (g & 31) << 2;
        *reinterpret_cast<float4*>(&xs[r][c]) = ld4(&x[(mt * 64 + r) * CCH + c]);
    }
    #pragma unroll
    for (int f = 0; f < 8; ++f) {
        int g = f * 256 + t;
        int r = g >> 4, c = (g & 15) << 2;
        *reinterpret_cast<float4*>(&ws[r][c]) = ld4(&wqkv[r * 384 + nt * 64 + c]);
    }
    __syncthreads();

    const int r0 = (t >> 4) << 2;
    const int c0 = (t & 15) << 2;
    float acc[4][4] = {};
    #pragma unroll 8
    for (int k4 = 0; k4 < 32; ++k4) {
        float a[4][4], b[4][4];
        #pragma unroll
        for (int i = 0; i < 4; ++i) {
            float4 v = ld4(&xs[r0 + i][k4 * 4]);
            a[i][0] = v.x; a[i][1] = v.y; a[i][2] = v.z; a[i][3] = v.w;
        }
        #pragma unroll
        for (int kk = 0; kk < 4; ++kk) {
            float4 v = ld4(&ws[k4 * 4 + kk][c0]);
            b[kk][0] = v.x; b[kk][1] = v.y; b[kk][2] = v.z; b[kk][3] = v.w;
        }
        #pragma unroll
        for (int i = 0; i < 4; ++i)
            #pragma unroll
            for (int kk = 0; kk < 4; ++kk)
                #pragma unroll
                for (int j = 0; j < 4; ++j)
                    acc[i][j] += a[i][kk] * b[kk][j];
    }

    const int head  = nt / 3;
    const int which = nt - 3 * head;
    const int gi0 = mt * 64 + r0;
    const int bb  = gi0 >> 12;
    const int n0  = gi0 & 4095;
    const int bhh = bb * 2 + head;

    if (which == 0) {              // Q, scale folded
        #pragma unroll
        for (int i = 0; i < 4; ++i) {
            uint2 u;
            u.x = f2bf(acc[i][0] * QK_SCALE) | ((unsigned)f2bf(acc[i][1] * QK_SCALE) << 16);
            u.y = f2bf(acc[i][2] * QK_SCALE) | ((unsigned)f2bf(acc[i][3] * QK_SCALE) << 16);
            *reinterpret_cast<uint2*>(&Qb[((size_t)(bhh * NT + n0 + i)) * HD + c0]) = u;
        }
    } else if (which == 1) {       // K
        #pragma unroll
        for (int i = 0; i < 4; ++i) {
            uint2 u;
            u.x = f2bf(acc[i][0]) | ((unsigned)f2bf(acc[i][1]) << 16);
            u.y = f2bf(acc[i][2]) | ((unsigned)f2bf(acc[i][3]) << 16);
            *reinterpret_cast<uint2*>(&Kb[((size_t)(bhh * NT + n0 + i)) * HD + c0]) = u;
        }
    } else {                       // V, transposed store [d][n]
        #pragma unroll
        for (int jj = 0; jj < 4; ++jj) {
            uint2 u;
            u.x = f2bf(acc[0][jj]) | ((unsigned)f2bf(acc[1][jj]) << 16);
            u.y = f2bf(acc[2][jj]) | ((unsigned)f2bf(acc[3][jj]) << 16);
            *reinterpret_cast<uint2*>(&Vt[((size_t)(bhh * HD + c0 + jj)) * NT + n0]) = u;
        }
    }
}

// ---------------- Kernel 2: flash attention, SWAPPED bf16 MFMA ----------------
// grid (64, 8). 4 waves x 16 q-rows. Computes S^T = mfma(K,Q) so each lane owns
// one q-row (q = lane&15): softmax is in-register + 2 shfls (vs 32).
// PV swapped too: O^T = mfma(V^T, P^T). K/V frag reads identical to prior round.
// P strip per wave: [16 q][64 j] bf16, row stride 144B, granule swizzle
// g' = (g + 2q) & 7  (write b64 2-way free, read b128 perfectly even).
__global__ __launch_bounds__(256) void k_attn(const unsigned short* __restrict__ Qb,
                                              const unsigned short* __restrict__ Kb,
                                              const unsigned short* __restrict__ Vt,
                                              float* __restrict__ R) {
    __shared__ __align__(16) char smem[41984];
    char* KsB = smem;             // [2][8192]
    char* VsB = smem + 16384;     // [2][8192]
    char* PwA = smem + 32768;     // [4][2304]

    const int t    = threadIdx.x;
    const int lane = t & 63;
    const int w    = t >> 6;
    const int qt   = blockIdx.x;
    const int bh   = blockIdx.y;

    const char* KbT = (const char*)Kb + (size_t)bh * NT * HD * 2;
    const char* VtT = (const char*)Vt + (size_t)bh * HD * NT * 2;

    const int q  = lane & 15;
    const int Lw = lane >> 4;

    // Q B-fragments in registers: lane -> Q[row=q][d = Lw*8 + i + 32*ks]
    short8 qa[2];
    {
        const int qrow = qt * 64 + w * 16 + q;
        const char* qp = (const char*)Qb +
            (((size_t)bh * NT + qrow) * HD + (Lw * 8)) * 2;
        qa[0] = *reinterpret_cast<const short8*>(qp);
        qa[1] = *reinterpret_cast<const short8*>(qp + 64);
    }

    char* Pw   = PwA + w * 2304;
    char* Prow = Pw + q * 144;

    float mrow = -1e30f, lrow = 0.f;
    f32x4 oacc[4];
    #pragma unroll
    for (int i = 0; i < 4; ++i) oacc[i] = (f32x4)0.f;

    const int rc0 = t >> 3;        // staging row for issue 0 (0..31)
    const int sp  = t & 7;         // physical slot
    const int rc1 = rc0 + 32;      // staging row for issue 1

    auto stage = [&](int buf, int kt) {
        const char* ksrc = KbT + (size_t)kt * 64 * 128;   // K rows kt*64.., 128B/row
        const char* vsrc = VtT + (size_t)kt * 128;        // Vt: d*8192 + kt*128
        __builtin_amdgcn_global_load_lds(
            (const __attribute__((address_space(1))) void*)(ksrc + rc0 * 128 + ((sp ^ (rc0 & 7)) * 16)),
            (__attribute__((address_space(3))) void*)(KsB + buf * 8192 + t * 16), 16, 0, 0);
        __builtin_amdgcn_global_load_lds(
            (const __attribute__((address_space(1))) void*)(ksrc + rc1 * 128 + ((sp ^ (rc1 & 7)) * 16)),
            (__attribute__((address_space(3))) void*)(KsB + buf * 8192 + 4096 + t * 16), 16, 0, 0);
        __builtin_amdgcn_global_load_lds(
            (const __attribute__((address_space(1))) void*)(vsrc + (size_t)rc0 * 8192 + ((sp ^ (rc0 & 7)) * 16)),
            (__attribute__((address_space(3))) void*)(VsB + buf * 8192 + t * 16), 16, 0, 0);
        __builtin_amdgcn_global_load_lds(
            (const __attribute__((address_space(1))) void*)(vsrc + (size_t)rc1 * 8192 + ((sp ^ (rc1 & 7)) * 16)),
            (__attribute__((address_space(3))) void*)(VsB + buf * 8192 + 4096 + t * 16), 16, 0, 0);
    };

    int cur = 0;
    stage(0, 0);
    __syncthreads();   // drains vmcnt -> tile 0 resident

    for (int kt = 0; kt < 64; ++kt) {
        if (kt < 63) stage(cur ^ 1, kt + 1);

        const char* KsC = KsB + cur * 8192;
        const char* VsC = VsB + cur * 8192;

        // ---- S^T = K (Q*scale)^T : lane holds S[j = 16ct+4Lw+reg][q] ----
        f32x4 sacc[4];
        #pragma unroll
        for (int ct = 0; ct < 4; ++ct) sacc[ct] = (f32x4)0.f;
        #pragma unroll
        for (int ct = 0; ct < 4; ++ct) {
            const int j = ct * 16 + q;
            #pragma unroll
            for (int ks = 0; ks < 2; ++ks) {
                const int slot = (Lw + 4 * ks) ^ (lane & 7);
                short8 kb = *reinterpret_cast<const short8*>(KsC + j * 128 + slot * 16);
                sacc[ct] = __builtin_amdgcn_mfma_f32_16x16x32_bf16(kb, qa[ks], sacc[ct], 0, 0, 0);
            }
        }

        // ---- online softmax: one q-row per lane, in-register + 2 shfls ----
        float mx = -1e30f;
        #pragma unroll
        for (int ct = 0; ct < 4; ++ct)
            #pragma unroll
            for (int r = 0; r < 4; ++r) mx = fmaxf(mx, sacc[ct][r]);
        mx = fmaxf(mx, __shfl_xor(mx, 16));
        mx = fmaxf(mx, __shfl_xor(mx, 32));
        const float mn = fmaxf(mrow, mx);
        const float corr = __expf(mrow - mn);
        mrow = mn;
        float e[4][4];
        float sum = 0.f;
        #pragma unroll
        for (int ct = 0; ct < 4; ++ct)
            #pragma unroll
            for (int r = 0; r < 4; ++r) {
                float ev = __expf(sacc[ct][r] - mn);
                e[ct][r] = ev;
                sum += ev;
            }
        sum += __shfl_xor(sum, 16);
        sum += __shfl_xor(sum, 32);
        lrow = lrow * corr + sum;
        #pragma unroll
        for (int dt = 0; dt < 4; ++dt) oacc[dt] *= corr;

        // ---- P[q][j] -> LDS strip (b64 writes, rotation swizzle) ----
        #pragma unroll
        for (int ct = 0; ct < 4; ++ct) {
            __hip_bfloat162 lo2 = __float22bfloat162_rn(make_float2(e[ct][0], e[ct][1]));
            __hip_bfloat162 hi2 = __float22bfloat162_rn(make_float2(e[ct][2], e[ct][3]));
            const int g = 2 * ct + (Lw >> 1);
            uint2 u = make_uint2(*reinterpret_cast<unsigned*>(&lo2),
                                 *reinterpret_cast<unsigned*>(&hi2));
            *reinterpret_cast<uint2*>(Prow + (((g + 2 * q) & 7) << 4) + ((Lw & 1) << 3)) = u;
        }

        // ---- P B-frags: lane -> P[q][j = Lw*8 + i + 32ks] (b128 reads) ----
        short8 pb[2];
        #pragma unroll
        for (int ks = 0; ks < 2; ++ks)
            pb[ks] = *reinterpret_cast<const short8*>(
                Prow + (((Lw + 4 * ks + 2 * q) & 7) << 4));

        // ---- O^T += V^T P^T : lane holds O[q][d = 16dt+4Lw+reg] ----
        #pragma unroll
        for (int dt = 0; dt < 4; ++dt) {
            const int d = dt * 16 + q;
            #pragma unroll
            for (int ks = 0; ks < 2; ++ks) {
                const int slot = (Lw + 4 * ks) ^ (lane & 7);
                short8 vb = *reinterpret_cast<const short8*>(VsC + d * 128 + slot * 16);
                oacc[dt] = __builtin_amdgcn_mfma_f32_16x16x32_bf16(vb, pb[ks], oacc[dt], 0, 0, 0);
            }
        }

        __syncthreads();   // drain next-tile staging; protect cur before reuse
        cur ^= 1;
    }

    // ---- epilogue: R[b*4096+row][h*64 + d], float4 per dt ----
    const int b = bh >> 1, h = bh & 1;
    const float inv = 1.0f / lrow;
    const int row = qt * 64 + w * 16 + q;
    float* dst = &R[((size_t)(b * NT + row)) * CCH + h * HD];
    #pragma unroll
    for (int dt = 0; dt < 4; ++dt) {
        float4 v = make_float4(oacc[dt][0] * inv, oacc[dt][1] * inv,
                               oacc[dt][2] * inv, oacc[dt][3] * inv);
        *reinterpret_cast<float4*>(&dst[dt * 16 + Lw * 4]) = v;
    }
}

// ---------------- Kernel 3: output projection + bias (fp32) ----------------
__global__ __launch_bounds__(256) void k_out(const float* __restrict__ R,
                                             const float* __restrict__ wout,
                                             const float* __restrict__ bout,
                                             float* __restrict__ out) {
    __shared__ float xs[64][132];
    __shared__ float ws[128][68];
    const int t  = threadIdx.x;
    const int mt = blockIdx.x;
    const int nt = blockIdx.y;

    #pragma unroll
    for (int f = 0; f < 8; ++f) {
        int g = f * 256 + t;
        int r = g >> 5, c = (g & 31) << 2;
        *reinterpret_cast<float4*>(&xs[r][c]) = ld4(&R[(mt * 64 + r) * CCH + c]);
    }
    #pragma unroll
    for (int f = 0; f < 8; ++f) {
        int g = f * 256 + t;
        int r = g >> 4, c = (g & 15) << 2;
        *reinterpret_cast<float4*>(&ws[r][c]) = ld4(&wout[r * CCH + nt * 64 + c]);
    }
    __syncthreads();

    const int r0 = (t >> 4) << 2;
    const int c0 = (t & 15) << 2;
    float acc[4][4] = {};
    #pragma unroll 8
    for (int k4 = 0; k4 < 32; ++k4) {
        float a[4][4], b[4][4];
        #pragma unroll
        for (int i = 0; i < 4; ++i) {
            float4 v = ld4(&xs[r0 + i][k4 * 4]);
            a[i][0] = v.x; a[i][1] = v.y; a[i][2] = v.z; a[i][3] = v.w;
        }
        #pragma unroll
        for (int kk = 0; kk < 4; ++kk) {
            float4 v = ld4(&ws[k4 * 4 + kk][c0]);
            b[kk][0] = v.x; b[kk][1] = v.y; b[kk][2] = v.z; b[kk][3] = v.w;
        }
        #pragma unroll
        for (int i = 0; i < 4; ++i)
            #pragma unroll
            for (int kk = 0; kk < 4; ++kk)
                #pragma unroll
                for (int j = 0; j < 4; ++j)
                    acc[i][j] += a[i][kk] * b[kk][j];
    }

    float4 bias = ld4(&bout[nt * 64 + c0]);
    #pragma unroll
    for (int i = 0; i < 4; ++i) {
        int gi = mt * 64 + r0 + i;
        float4 v = make_float4(acc[i][0] + bias.x, acc[i][1] + bias.y,
                               acc[i][2] + bias.z, acc[i][3] + bias.w);
        *reinterpret_cast<float4*>(&out[(size_t)gi * CCH + nt * 64 + c0]) = v;
    }
}

extern "C" void kernel_launch(void* const* d_in, const int* in_sizes, int n_in,
                              void* d_out, int out_size, void* d_ws, size_t ws_size,
                              hipStream_t stream) {
    const float* x    = (const float*)d_in[0];
    const float* wqkv = (const float*)d_in[1];
    const float* wout = (const float*)d_in[2];
    const float* bout = (const float*)d_in[3];
    float* out = (float*)d_out;

    // workspace: Qb/Kb/Vt bf16 (4MB each), R fp32 (8MB) = 20MB
    unsigned short* Qb = (unsigned short*)d_ws;
    unsigned short* Kb = Qb + 2097152;
    unsigned short* Vt = Kb + 2097152;
    float* R = (float*)((char*)d_ws + 12 * 1024 * 1024);

    k_qkv<<<dim3(256, 6), 256, 0, stream>>>(x, wqkv, Qb, Kb, Vt);
    k_attn<<<dim3(64, 8), 256, 0, stream>>>(Qb, Kb, Vt, R);
    k_out<<<dim3(256, 2), 256, 0, stream>>>(R, wout, bout, out);
}

// Round 11
// 162.524 us; speedup vs baseline: 4.4842x; 1.1908x over previous
//
#include <hip/hip_runtime.h>
#include <hip/hip_bf16.h>

#define NT 4096
#define HD 64
#define CCH 128
#define LOG2E 1.4426950408889634f
#define QK_SCALE 0.08838834764831845f      // 128^-0.5 (reference scales by C)
#define QSCALE_LOG2 (QK_SCALE * LOG2E)     // folded so softmax uses exp2 directly

typedef __attribute__((ext_vector_type(8))) short short8;   // 8 bf16 (4 VGPR)
typedef __attribute__((ext_vector_type(4))) float f32x4;

__device__ __forceinline__ float4 ld4(const float* p) {
    return *reinterpret_cast<const float4*>(p);
}

__device__ __forceinline__ unsigned short f2bf(float f) {  // RNE float->bf16
    union { float f; unsigned u; } v; v.f = f;
    unsigned r = v.u + 0x7fff + ((v.u >> 16) & 1);
    return (unsigned short)(r >> 16);
}

__device__ __forceinline__ unsigned pkbf(float a, float b) {  // pack 2 bf16 (RNE)
    __hip_bfloat162 h = __float22bfloat162_rn(make_float2(a, b));
    return *reinterpret_cast<unsigned*>(&h);
}

__device__ __forceinline__ float exp2fast(float x) {
#if __has_builtin(__builtin_amdgcn_exp2f)
    return __builtin_amdgcn_exp2f(x);
#else
    return exp2f(x);
#endif
}

// ---------------- Kernel 1: QKV projection, bf16 MFMA ----------------
// x:[16384,128] fp32 -> bf16, @ wqkv cols nt*64..+63 -> Qb(scaled)/Kb/Vt(bf16).
// LDS tiles xs[64 rows][128 k] and wt[64 j][128 k] bf16, granule-XOR swizzled
// (g ^= row&7) -- same verified pattern as k_attn's K tile.
__global__ __launch_bounds__(256) void k_qkv(const float* __restrict__ x,
                                             const float* __restrict__ wqkv,
                                             unsigned short* __restrict__ Qb,
                                             unsigned short* __restrict__ Kb,
                                             unsigned short* __restrict__ Vt) {
    __shared__ __align__(16) unsigned short xs[64][128];
    __shared__ __align__(16) unsigned short wt[64][128];
    const int t  = threadIdx.x;
    const int mt = blockIdx.x;
    const int nt = blockIdx.y;

    // ---- stage x-tile: thread -> row r=t>>2, 32-col quarter qd=t&3 ----
    {
        const int r = t >> 2, qd = t & 3;
        const float* src = &x[(size_t)(mt * 64 + r) * CCH + qd * 32];
        unsigned pk[16];
        #pragma unroll
        for (int i = 0; i < 8; ++i) {
            float4 v = ld4(src + i * 4);
            pk[2 * i]     = pkbf(v.x, v.y);
            pk[2 * i + 1] = pkbf(v.z, v.w);
        }
        #pragma unroll
        for (int g2 = 0; g2 < 4; ++g2) {
            const int gp = (qd * 4 + g2) ^ (r & 7);
            *reinterpret_cast<uint4*>(&xs[r][gp * 8]) =
                make_uint4(pk[4 * g2], pk[4 * g2 + 1], pk[4 * g2 + 2], pk[4 * g2 + 3]);
        }
    }
    // ---- stage w^T-tile: thread -> k-granule g=t>>4 (8 k's), 4 j's ----
    {
        const int g  = t >> 4;
        const int j4 = (t & 15) * 4;
        float4 col[8];
        #pragma unroll
        for (int kk = 0; kk < 8; ++kk)
            col[kk] = ld4(&wqkv[(size_t)(g * 8 + kk) * 384 + nt * 64 + j4]);
        const float* c = reinterpret_cast<const float*>(col);
        #pragma unroll
        for (int jj = 0; jj < 4; ++jj) {
            const int j = j4 + jj;
            unsigned a0 = pkbf(c[0 * 4 + jj], c[1 * 4 + jj]);
            unsigned a1 = pkbf(c[2 * 4 + jj], c[3 * 4 + jj]);
            unsigned a2 = pkbf(c[4 * 4 + jj], c[5 * 4 + jj]);
            unsigned a3 = pkbf(c[6 * 4 + jj], c[7 * 4 + jj]);
            *reinterpret_cast<uint4*>(&wt[j][(g ^ (j & 7)) * 8]) = make_uint4(a0, a1, a2, a3);
        }
    }
    __syncthreads();

    const int lane = t & 63, w = t >> 6, q = lane & 15, Lw = lane >> 4;

    // A-frags: lane -> x-row (w*16+q), k = Lw*8 + i + 32ks  (row&7 == q&7)
    short8 qa4[4];
    #pragma unroll
    for (int ks = 0; ks < 4; ++ks)
        qa4[ks] = *reinterpret_cast<const short8*>(
            &xs[w * 16 + q][((Lw + 4 * ks) ^ (q & 7)) * 8]);

    f32x4 acc[4];
    #pragma unroll
    for (int ct = 0; ct < 4; ++ct) acc[ct] = (f32x4)0.f;
    #pragma unroll
    for (int ct = 0; ct < 4; ++ct) {
        const int j = ct * 16 + q;
        #pragma unroll
        for (int ks = 0; ks < 4; ++ks) {
            short8 wb = *reinterpret_cast<const short8*>(
                &wt[j][((Lw + 4 * ks) ^ (j & 7)) * 8]);
            acc[ct] = __builtin_amdgcn_mfma_f32_16x16x32_bf16(qa4[ks], wb, acc[ct], 0, 0, 0);
        }
    }

    // ---- epilogue: D col = ct*16+q, row = Lw*4+reg ----
    const int head  = nt / 3;
    const int which = nt - 3 * head;
    const int gi0 = mt * 64 + w * 16 + Lw * 4;   // 4-aligned: no batch crossing
    const int bb  = gi0 >> 12;
    const int n0  = gi0 & 4095;
    const int bhh = bb * 2 + head;

    if (which == 0) {              // Q, scale*log2e folded
        #pragma unroll
        for (int ct = 0; ct < 4; ++ct) {
            const int d = ct * 16 + q;
            #pragma unroll
            for (int r = 0; r < 4; ++r)
                Qb[((size_t)(bhh * NT + n0 + r)) * HD + d] = f2bf(acc[ct][r] * QSCALE_LOG2);
        }
    } else if (which == 1) {       // K
        #pragma unroll
        for (int ct = 0; ct < 4; ++ct) {
            const int d = ct * 16 + q;
            #pragma unroll
            for (int r = 0; r < 4; ++r)
                Kb[((size_t)(bhh * NT + n0 + r)) * HD + d] = f2bf(acc[ct][r]);
        }
    } else {                       // V transposed [d][n], 4 consecutive n packed
        #pragma unroll
        for (int ct = 0; ct < 4; ++ct) {
            const int d = ct * 16 + q;
            uint2 u;
            u.x = pkbf(acc[ct][0], acc[ct][1]);
            u.y = pkbf(acc[ct][2], acc[ct][3]);
            *reinterpret_cast<uint2*>(&Vt[((size_t)(bhh * HD + d)) * NT + n0]) = u;
        }
    }
}

// ---------------- Kernel 2: flash attention, SWAPPED bf16 MFMA ----------------
// Same structure as validated round-9 kernel; changes: exp2-domain softmax
// (log2e folded into Qb) and hoisted staging pointers + unroll-by-2 buffers.
__global__ __launch_bounds__(256) void k_attn(const unsigned short* __restrict__ Qb,
                                              const unsigned short* __restrict__ Kb,
                                              const unsigned short* __restrict__ Vt,
                                              float* __restrict__ R) {
    __shared__ __align__(16) char smem[41984];
    char* Ks0 = smem;              // [8192] buf0 K
    char* Ks1 = smem + 8192;       // buf1 K
    char* Vs0 = smem + 16384;
    char* Vs1 = smem + 24576;
    char* PwA = smem + 32768;      // [4][2304]

    const int t    = threadIdx.x;
    const int lane = t & 63;
    const int w    = t >> 6;
    const int qt   = blockIdx.x;
    const int bh   = blockIdx.y;

    const char* KbT = (const char*)Kb + (size_t)bh * NT * HD * 2;
    const char* VtT = (const char*)Vt + (size_t)bh * HD * NT * 2;

    const int q  = lane & 15;
    const int Lw = lane >> 4;

    short8 qa[2];
    {
        const int qrow = qt * 64 + w * 16 + q;
        const char* qp = (const char*)Qb +
            (((size_t)bh * NT + qrow) * HD + (Lw * 8)) * 2;
        qa[0] = *reinterpret_cast<const short8*>(qp);
        qa[1] = *reinterpret_cast<const short8*>(qp + 64);
    }

    char* Prow = PwA + w * 2304 + q * 144;

    float mrow = -1e30f, lrow = 0.f;
    f32x4 oacc[4];
    #pragma unroll
    for (int i = 0; i < 4; ++i) oacc[i] = (f32x4)0.f;

    const int rc0 = t >> 3;
    const int sp  = t & 7;
    const int rc1 = rc0 + 32;

    // hoisted staging pointers (advance by constants each tile)
    const char* kp0 = KbT + rc0 * 128 + (sp ^ (rc0 & 7)) * 16;
    const char* kp1 = KbT + rc1 * 128 + (sp ^ (rc1 & 7)) * 16;
    const char* vp0 = VtT + (size_t)rc0 * 8192 + (sp ^ (rc0 & 7)) * 16;
    const char* vp1 = VtT + (size_t)rc1 * 8192 + (sp ^ (rc1 & 7)) * 16;

    auto gll = [](const char* g, char* l) {
        __builtin_amdgcn_global_load_lds(
            (const __attribute__((address_space(1))) void*)g,
            (__attribute__((address_space(3))) void*)l, 16, 0, 0);
    };
    auto stage = [&](char* KsD, char* VsD) {
        gll(kp0, KsD + t * 16); gll(kp1, KsD + 4096 + t * 16);
        gll(vp0, VsD + t * 16); gll(vp1, VsD + 4096 + t * 16);
        kp0 += 8192; kp1 += 8192; vp0 += 128; vp1 += 128;
    };

    auto compute = [&](const char* KsC, const char* VsC) {
        // S^T = K Q^T (log2 domain): lane holds S[j=16ct+4Lw+reg][q]
        f32x4 sacc[4];
        #pragma unroll
        for (int ct = 0; ct < 4; ++ct) sacc[ct] = (f32x4)0.f;
        #pragma unroll
        for (int ct = 0; ct < 4; ++ct) {
            const int j = ct * 16 + q;
            #pragma unroll
            for (int ks = 0; ks < 2; ++ks) {
                const int slot = (Lw + 4 * ks) ^ (lane & 7);
                short8 kb = *reinterpret_cast<const short8*>(KsC + j * 128 + slot * 16);
                sacc[ct] = __builtin_amdgcn_mfma_f32_16x16x32_bf16(kb, qa[ks], sacc[ct], 0, 0, 0);
            }
        }
        // online softmax (exp2 domain), one q-row per lane
        float mx = -1e30f;
        #pragma unroll
        for (int ct = 0; ct < 4; ++ct)
            #pragma unroll
            for (int r = 0; r < 4; ++r) mx = fmaxf(mx, sacc[ct][r]);
        mx = fmaxf(mx, __shfl_xor(mx, 16));
        mx = fmaxf(mx, __shfl_xor(mx, 32));
        const float mn = fmaxf(mrow, mx);
        const float corr = exp2fast(mrow - mn);
        mrow = mn;
        float e[4][4];
        float sum = 0.f;
        #pragma unroll
        for (int ct = 0; ct < 4; ++ct)
            #pragma unroll
            for (int r = 0; r < 4; ++r) {
                float ev = exp2fast(sacc[ct][r] - mn);
                e[ct][r] = ev;
                sum += ev;
            }
        sum += __shfl_xor(sum, 16);
        sum += __shfl_xor(sum, 32);
        lrow = lrow * corr + sum;
        #pragma unroll
        for (int dt = 0; dt < 4; ++dt) oacc[dt] *= corr;

        // P[q][j] -> wave-private strip (rotation swizzle)
        #pragma unroll
        for (int ct = 0; ct < 4; ++ct) {
            const int g = 2 * ct + (Lw >> 1);
            uint2 u = make_uint2(pkbf(e[ct][0], e[ct][1]), pkbf(e[ct][2], e[ct][3]));
            *reinterpret_cast<uint2*>(Prow + (((g + 2 * q) & 7) << 4) + ((Lw & 1) << 3)) = u;
        }
        short8 pb[2];
        #pragma unroll
        for (int ks = 0; ks < 2; ++ks)
            pb[ks] = *reinterpret_cast<const short8*>(
                Prow + (((Lw + 4 * ks + 2 * q) & 7) << 4));

        // O^T += V^T P^T
        #pragma unroll
        for (int dt = 0; dt < 4; ++dt) {
            const int d = dt * 16 + q;
            #pragma unroll
            for (int ks = 0; ks < 2; ++ks) {
                const int slot = (Lw + 4 * ks) ^ (lane & 7);
                short8 vb = *reinterpret_cast<const short8*>(VsC + d * 128 + slot * 16);
                oacc[dt] = __builtin_amdgcn_mfma_f32_16x16x32_bf16(vb, pb[ks], oacc[dt], 0, 0, 0);
            }
        }
    };

    stage(Ks0, Vs0);            // kt 0
    __syncthreads();
    for (int it = 0; it < 32; ++it) {
        stage(Ks1, Vs1);        // kt 2it+1 (always exists)
        compute(Ks0, Vs0);      // kt 2it
        __syncthreads();
        if (it < 31) stage(Ks0, Vs0);   // kt 2it+2
        compute(Ks1, Vs1);      // kt 2it+1
        __syncthreads();
    }

    // epilogue: R[b*4096+row][h*64 + d]
    const int b = bh >> 1, h = bh & 1;
    const float inv = 1.0f / lrow;
    const int row = qt * 64 + w * 16 + q;
    float* dst = &R[((size_t)(b * NT + row)) * CCH + h * HD];
    #pragma unroll
    for (int dt = 0; dt < 4; ++dt) {
        float4 v = make_float4(oacc[dt][0] * inv, oacc[dt][1] * inv,
                               oacc[dt][2] * inv, oacc[dt][3] * inv);
        *reinterpret_cast<float4*>(&dst[dt * 16 + Lw * 4]) = v;
    }
}

// ---------------- Kernel 3: output projection + bias (fp32) ----------------
__global__ __launch_bounds__(256) void k_out(const float* __restrict__ R,
                                             const float* __restrict__ wout,
                                             const float* __restrict__ bout,
                                             float* __restrict__ out) {
    __shared__ float xs[64][132];
    __shared__ float ws[128][68];
    const int t  = threadIdx.x;
    const int mt = blockIdx.x;
    const int nt = blockIdx.y;

    #pragma unroll
    for (int f = 0; f < 8; ++f) {
        int g = f * 256 + t;
        int r = g >> 5, c = (g & 31) << 2;
        *reinterpret_cast<float4*>(&xs[r][c]) = ld4(&R[(mt * 64 + r) * CCH + c]);
    }
    #pragma unroll
    for (int f = 0; f < 8; ++f) {
        int g = f * 256 + t;
        int r = g >> 4, c = (g & 15) << 2;
        *reinterpret_cast<float4*>(&ws[r][c]) = ld4(&wout[r * CCH + nt * 64 + c]);
    }
    __syncthreads();

    const int r0 = (t >> 4) << 2;
    const int c0 = (t & 15) << 2;
    float acc[4][4] = {};
    #pragma unroll 8
    for (int k4 = 0; k4 < 32; ++k4) {
        float a[4][4], b[4][4];
        #pragma unroll
        for (int i = 0; i < 4; ++i) {
            float4 v = ld4(&xs[r0 + i][k4 * 4]);
            a[i][0] = v.x; a[i][1] = v.y; a[i][2] = v.z; a[i][3] = v.w;
        }
        #pragma unroll
        for (int kk = 0; kk < 4; ++kk) {
            float4 v = ld4(&ws[k4 * 4 + kk][c0]);
            b[kk][0] = v.x; b[kk][1] = v.y; b[kk][2] = v.z; b[kk][3] = v.w;
        }
        #pragma unroll
        for (int i = 0; i < 4; ++i)
            #pragma unroll
            for (int kk = 0; kk < 4; ++kk)
                #pragma unroll
                for (int j = 0; j < 4; ++j)
                    acc[i][j] += a[i][kk] * b[kk][j];
    }

    float4 bias = ld4(&bout[nt * 64 + c0]);
    #pragma unroll
    for (int i = 0; i < 4; ++i) {
        int gi = mt * 64 + r0 + i;
        float4 v = make_float4(acc[i][0] + bias.x, acc[i][1] + bias.y,
                               acc[i][2] + bias.z, acc[i][3] + bias.w);
        *reinterpret_cast<float4*>(&out[(size_t)gi * CCH + nt * 64 + c0]) = v;
    }
}

extern "C" void kernel_launch(void* const* d_in, const int* in_sizes, int n_in,
                              void* d_out, int out_size, void* d_ws, size_t ws_size,
                              hipStream_t stream) {
    const float* x    = (const float*)d_in[0];
    const float* wqkv = (const float*)d_in[1];
    const float* wout = (const float*)d_in[2];
    const float* bout = (const float*)d_in[3];
    float* out = (float*)d_out;

    // workspace: Qb/Kb/Vt bf16 (4MB each), R fp32 (8MB) = 20MB
    unsigned short* Qb = (unsigned short*)d_ws;
    unsigned short* Kb = Qb + 2097152;
    unsigned short* Vt = Kb + 2097152;
    float* R = (float*)((char*)d_ws + 12 * 1024 * 1024);

    k_qkv<<<dim3(256, 6), 256, 0, stream>>>(x, wqkv, Qb, Kb, Vt);
    k_attn<<<dim3(64, 8), 256, 0, stream>>>(Qb, Kb, Vt, R);
    k_out<<<dim3(256, 2), 256, 0, stream>>>(R, wout, bout, out);
}